// Round 4
// baseline (1007.174 us; speedup 1.0000x reference)
//
#include <hip/hip_runtime.h>

typedef __bf16 bf16x8 __attribute__((ext_vector_type(8)));
typedef float f32x4 __attribute__((ext_vector_type(4)));
typedef float f32x16 __attribute__((ext_vector_type(16)));

#define MFMA16(a, b, c) __builtin_amdgcn_mfma_f32_16x16x32_bf16((a), (b), (c), 0, 0, 0)
#define MFMA32(a, b, c) __builtin_amdgcn_mfma_f32_32x32x16_bf16((a), (b), (c), 0, 0, 0)

static constexpr int SEQ = 4096;
static constexpr int DIM = 512;

typedef __attribute__((address_space(3))) void lds_void;
typedef __attribute__((address_space(1))) const void gbl_void;

// async global->LDS, 16B per lane; LDS dest = wave-uniform base + lane*16
__device__ __forceinline__ void glds16(const void* g, void* l) {
    __builtin_amdgcn_global_load_lds((gbl_void*)g, (lds_void*)l, 16, 0, 0);
}

__device__ __forceinline__ bf16x8 cvt8f(const float* __restrict__ p) {
    float4 f0 = *(const float4*)p;
    float4 f1 = *(const float4*)(p + 4);
    bf16x8 v;
    v[0] = (__bf16)f0.x; v[1] = (__bf16)f0.y; v[2] = (__bf16)f0.z; v[3] = (__bf16)f0.w;
    v[4] = (__bf16)f1.x; v[5] = (__bf16)f1.y; v[6] = (__bf16)f1.z; v[7] = (__bf16)f1.w;
    return v;
}

// ---------------------------------------------------------------------------
// Weight convert: 4 x [512][512] fp32 -> bf16 slab
// ---------------------------------------------------------------------------
__global__ __launch_bounds__(256)
void convert_w(const float* __restrict__ wq, const float* __restrict__ wk,
               const float* __restrict__ wv, const float* __restrict__ wo,
               __bf16* __restrict__ out)
{
    const int z = blockIdx.y;
    const float* src = (z == 0) ? wq : (z == 1) ? wk : (z == 2) ? wv : wo;
    __bf16* dst = out + (size_t)z * DIM * DIM;
    const int i = (blockIdx.x * 256 + threadIdx.x) * 8;
    *(bf16x8*)(dst + i) = cvt8f(src + i);
}

// ---------------------------------------------------------------------------
// QKV projection GEMM (m97-style): C = A(fp32) @ W(bf16)^T. 128x128, BK=64.
// global_load_lds staging (A stays fp32 in LDS; cvt at fragment read).
// z==2 (V) writes output transposed into Vt[d][s] via LDS-transpose epilogue.
// ---------------------------------------------------------------------------
__global__ __launch_bounds__(256, 3)
void gemm_qkv(const float* __restrict__ q, const float* __restrict__ k,
              const float* __restrict__ v, const __bf16* __restrict__ wbf,
              __bf16* __restrict__ Qp, __bf16* __restrict__ Kp,
              __bf16* __restrict__ Vt)
{
    __shared__ __align__(16) char smem[49152];   // Af 32KB + Bs 16KB (Tt reuses)
    float* Af  = (float*)smem;                   // [128][64] fp32
    __bf16* Bs = (__bf16*)(smem + 32768);        // [128][64] bf16

    const int z = blockIdx.z;
    const float* Ap = (z == 0) ? q : (z == 1) ? k : v;
    const __bf16* Bp = wbf + (size_t)z * DIM * DIM;

    const int tid  = threadIdx.x;
    const int wave = tid >> 6;
    const int lane = tid & 63;
    const int quad = lane >> 4;
    const int l16  = lane & 15;
    const int m0 = blockIdx.x * 128;
    const int n0 = blockIdx.y * 128;
    const int wm = (wave >> 1) * 64;
    const int wn = (wave & 1) * 64;

    f32x4 acc[4][4] = {};

    for (int k0 = 0; k0 < DIM; k0 += 64) {
        #pragma unroll
        for (int i = 0; i < 8; i++) {          // A: 32 instrs, 8/wave
            const int j = wave * 8 + i;
            const int c = j * 64 + lane;
            const int row = c >> 4, f4 = c & 15;
            glds16(Ap + (size_t)(m0 + row) * DIM + k0 + f4 * 4, &Af[j * 256]);
        }
        #pragma unroll
        for (int i = 0; i < 4; i++) {          // B: 16 instrs, 4/wave
            const int j = wave * 4 + i;
            const int c = j * 64 + lane;
            const int row = c >> 3, c8 = c & 7;
            glds16(Bp + (size_t)(n0 + row) * DIM + k0 + c8 * 8, &Bs[j * 512]);
        }
        __syncthreads();
        #pragma unroll
        for (int kk = 0; kk < 2; kk++) {
            bf16x8 af[4], bg[4];
            #pragma unroll
            for (int mt = 0; mt < 4; mt++) {
                const int r = wm + mt * 16 + l16;
                af[mt] = cvt8f(&Af[r * 64 + kk * 32 + quad * 8]);
            }
            #pragma unroll
            for (int nt = 0; nt < 4; nt++) {
                const int r = wn + nt * 16 + l16;
                bg[nt] = *(const bf16x8*)&Bs[r * 64 + kk * 32 + quad * 8];
            }
            #pragma unroll
            for (int mt = 0; mt < 4; mt++)
                #pragma unroll
                for (int nt = 0; nt < 4; nt++)
                    acc[mt][nt] = MFMA16(af[mt], bg[nt], acc[mt][nt]);
        }
        __syncthreads();
    }

    if (z < 2) {
        __bf16* Cp = (z == 0) ? Qp : Kp;
        #pragma unroll
        for (int mt = 0; mt < 4; mt++)
            #pragma unroll
            for (int nt = 0; nt < 4; nt++)
                #pragma unroll
                for (int r = 0; r < 4; r++)
                    Cp[(size_t)(m0 + wm + mt * 16 + quad * 4 + r) * DIM
                       + n0 + wn + nt * 16 + l16] = (__bf16)acc[mt][nt][r];
    } else {
        // transpose tile via LDS, write Vt[n][d][s]
        __bf16* Tt = (__bf16*)smem;            // [128][130]
        #pragma unroll
        for (int mt = 0; mt < 4; mt++)
            #pragma unroll
            for (int nt = 0; nt < 4; nt++)
                #pragma unroll
                for (int r = 0; r < 4; r++)
                    Tt[(wm + mt * 16 + quad * 4 + r) * 130 + wn + nt * 16 + l16]
                        = (__bf16)acc[mt][nt][r];
        __syncthreads();
        const int nb = m0 >> 12;
        const int s0 = m0 & 4095;
        const int d  = tid >> 1;
        const int sh = (tid & 1) * 64;
        __bf16* dst = Vt + (size_t)nb * DIM * SEQ + (size_t)(n0 + d) * SEQ + s0 + sh;
        #pragma unroll
        for (int i = 0; i < 8; i++) {
            bf16x8 vv;
            #pragma unroll
            for (int e = 0; e < 8; e++) vv[e] = Tt[(sh + i * 8 + e) * 130 + d];
            *(bf16x8*)(dst + i * 8) = vv;
        }
    }
}

// ---------------------------------------------------------------------------
// Output GEMM: C(fp32) = A(bf16) @ Wo(bf16)^T + bias. Same m97 structure.
// ---------------------------------------------------------------------------
__global__ __launch_bounds__(256, 3)
void gemm_out(const __bf16* __restrict__ Ap, const __bf16* __restrict__ Bp,
              float* __restrict__ Cp, const float* __restrict__ bias)
{
    __shared__ __align__(16) __bf16 As[128 * 64];
    __shared__ __align__(16) __bf16 Bs[128 * 64];
    const int tid  = threadIdx.x;
    const int wave = tid >> 6;
    const int lane = tid & 63;
    const int quad = lane >> 4;
    const int l16  = lane & 15;
    const int m0 = blockIdx.x * 128;
    const int n0 = blockIdx.y * 128;
    const int wm = (wave >> 1) * 64;
    const int wn = (wave & 1) * 64;

    f32x4 acc[4][4] = {};

    for (int k0 = 0; k0 < DIM; k0 += 64) {
        #pragma unroll
        for (int i = 0; i < 4; i++) {
            const int j = wave * 4 + i;
            const int c = j * 64 + lane;
            const int row = c >> 3, c8 = c & 7;
            glds16(Ap + (size_t)(m0 + row) * DIM + k0 + c8 * 8, &As[j * 512]);
            glds16(Bp + (size_t)(n0 + row) * DIM + k0 + c8 * 8, &Bs[j * 512]);
        }
        __syncthreads();
        #pragma unroll
        for (int kk = 0; kk < 2; kk++) {
            bf16x8 af[4], bg[4];
            #pragma unroll
            for (int mt = 0; mt < 4; mt++)
                af[mt] = *(const bf16x8*)&As[(wm + mt * 16 + l16) * 64 + kk * 32 + quad * 8];
            #pragma unroll
            for (int nt = 0; nt < 4; nt++)
                bg[nt] = *(const bf16x8*)&Bs[(wn + nt * 16 + l16) * 64 + kk * 32 + quad * 8];
            #pragma unroll
            for (int mt = 0; mt < 4; mt++)
                #pragma unroll
                for (int nt = 0; nt < 4; nt++)
                    acc[mt][nt] = MFMA16(af[mt], bg[nt], acc[mt][nt]);
        }
        __syncthreads();
    }
    #pragma unroll
    for (int mt = 0; mt < 4; mt++)
        #pragma unroll
        for (int nt = 0; nt < 4; nt++)
            #pragma unroll
            for (int r = 0; r < 4; r++) {
                const int col = n0 + wn + nt * 16 + l16;
                Cp[(size_t)(m0 + wm + mt * 16 + quad * 4 + r) * DIM + col]
                    = acc[mt][nt][r] + bias[col];
            }
}

// ---------------------------------------------------------------------------
// Flash attention v4: 1024 thr (16 waves), BM=64, BN=512, 8 iters.
// mfma 32x32x16 (A: m=l&31,k=(l>>5)*8+j; C: col=l&31,row=(reg&3)+8*(reg>>2)+4*(l>>5))
// Wave nw: score cols [32nw,+32), PV d-slice [32nw,+32) -> zero K/V duplication.
// Q & P in XOR-swizzled LDS. AO aliases Qp (row-exclusive per block).
// ---------------------------------------------------------------------------
__global__ __launch_bounds__(1024)
void flash_attn(__bf16* __restrict__ Qp, const __bf16* __restrict__ Kp,
                const __bf16* __restrict__ Vt, const int* __restrict__ mask)
{
    constexpr float SCALE = 0.044194173824159216f;   // 1/sqrt(512)

    __shared__ __bf16 Qs[64 * 512];     // 64 KB swizzled
    __shared__ __bf16 P[64 * 512];      // 64 KB swizzled
    __shared__ unsigned Wb2[16 * 64];   // mask bits [word][row], 4 KB
    __shared__ float pmax[16][68];
    __shared__ float psum[16][68];
    __shared__ float m_s[2][64];
    __shared__ float alpha_s[64];
    __shared__ float l_s[64];
    __shared__ unsigned flag_s;

    const int bid = blockIdx.x;
    const int n  = bid & 3;             // batch -> XCD-local K/V
    const int q0 = (bid >> 2) * 64;
    const int tid  = threadIdx.x;
    const int nw   = tid >> 6;          // 0..15
    const int lane = tid & 63;
    const int l32  = lane & 31;
    const int half = lane >> 5;

    const __bf16* Qb = Qp + (size_t)n * SEQ * DIM;
    const __bf16* Kb = Kp + (size_t)n * SEQ * DIM;
    const __bf16* Vb = Vt + (size_t)n * DIM * SEQ;
    const int*    Mb = mask + (size_t)n * SEQ * SEQ;
    __bf16*       AO = Qp + (size_t)n * SEQ * DIM;   // alias: rows consumed first

    // ---- stage Q once (swizzled 16B chunks)
    #pragma unroll
    for (int i = 0; i < 4; i++) {
        const int idx = i * 1024 + tid;
        const int row = idx >> 6;
        const int c   = idx & 63;
        const int pc  = (c & 56) | ((c & 7) ^ (row & 7));
        *(bf16x8*)&Qs[row * 512 + pc * 8] =
            *(const bf16x8*)(Qb + (size_t)(q0 + row) * DIM + c * 8);
    }
    if (tid < 64) { m_s[0][tid] = -__builtin_inff(); l_s[tid] = 0.f; }
    __syncthreads();

    f32x16 o0 = {}, o1 = {};

    for (int j = 0; j < 8; j++) {
        const int k0 = j * 512;
        const int jp = j & 1;

        // ---- mask bit-pack: thread -> (row = tid>>4, word = tid&15)
        {
            const int mr = tid >> 4, wd = tid & 15;
            const int* mp = Mb + (size_t)(q0 + mr) * SEQ + k0 + wd * 32;
            unsigned w = 0;
            #pragma unroll
            for (int c = 0; c < 8; c++) {
                int4 m4 = *(const int4*)(mp + c * 4);
                w |= (unsigned)(m4.x & 1) << (c * 4 + 0);
                w |= (unsigned)(m4.y & 1) << (c * 4 + 1);
                w |= (unsigned)(m4.z & 1) << (c * 4 + 2);
                w |= (unsigned)(m4.w & 1) << (c * 4 + 3);
            }
            Wb2[wd * 64 + mr] = w;
        }

        // ---- phase 1: scores, wave cols [32nw, +32), rows 0..63 (2 frags)
        f32x16 s0 = {}, s1 = {};
        {
            const __bf16* kb = Kb + (size_t)(k0 + nw * 32 + l32) * DIM + half * 8;
            #pragma unroll
            for (int ks = 0; ks < 32; ks++) {
                bf16x8 b = *(const bf16x8*)(kb + ks * 16);
                const int c = ks * 2 + half;
                const int r0 = l32, r1 = 32 + l32;
                bf16x8 a0 = *(const bf16x8*)&Qs[r0 * 512 + (((c & 56) | ((c & 7) ^ (r0 & 7)))) * 8];
                bf16x8 a1 = *(const bf16x8*)&Qs[r1 * 512 + (((c & 56) | ((c & 7) ^ (r1 & 7)))) * 8];
                s0 = MFMA32(a0, b, s0);
                s1 = MFMA32(a1, b, s1);
            }
        }
        // ---- per-row partial max over 32 cols (raw scores)
        #pragma unroll
        for (int rt = 0; rt < 2; rt++) {
            #pragma unroll
            for (int g2 = 0; g2 < 4; g2++) {
                f32x4 v;
                #pragma unroll
                for (int r = 0; r < 4; r++) v[r] = rt ? s1[g2 * 4 + r] : s0[g2 * 4 + r];
                #pragma unroll
                for (int d = 1; d < 32; d <<= 1) {
                    #pragma unroll
                    for (int r = 0; r < 4; r++) v[r] = fmaxf(v[r], __shfl_xor(v[r], d));
                }
                if (l32 == 0)
                    *(f32x4*)&pmax[nw][rt * 32 + g2 * 8 + half * 4] = v;
            }
        }
        __syncthreads();   // A

        // ---- combine (wave 0, one row per lane)
        if (nw == 0) {
            float mp_ = pmax[0][lane];
            #pragma unroll
            for (int w2 = 1; w2 < 16; w2++) mp_ = fmaxf(mp_, pmax[w2][lane]);
            mp_ *= SCALE;
            const float mo = m_s[jp][lane];
            const float mn = fmaxf(mo, mp_);
            m_s[jp ^ 1][lane] = mn;
            alpha_s[lane] = __expf(mo - mn);
            unsigned long long ch = __ballot(mn > mo);
            if (lane == 0) flag_s = (ch != 0ull);
        }
        __syncthreads();   // A2

        // ---- rescale O
        if (flag_s) {
            #pragma unroll
            for (int rt = 0; rt < 2; rt++)
                #pragma unroll
                for (int g2 = 0; g2 < 4; g2++) {
                    const f32x4 a4 = *(const f32x4*)&alpha_s[rt * 32 + g2 * 8 + half * 4];
                    #pragma unroll
                    for (int r = 0; r < 4; r++) {
                        if (rt) o1[g2 * 4 + r] *= a4[r];
                        else    o0[g2 * 4 + r] *= a4[r];
                    }
                }
        }
        // ---- exp, mask, write P, psum
        #pragma unroll
        for (int rt = 0; rt < 2; rt++) {
            #pragma unroll
            for (int g2 = 0; g2 < 4; g2++) {
                const int rowb = rt * 32 + g2 * 8 + half * 4;
                const f32x4 m4 = *(const f32x4*)&m_s[jp ^ 1][rowb];
                const uint4 w4 = *(const uint4*)&Wb2[nw * 64 + rowb];
                f32x4 ps;
                #pragma unroll
                for (int r = 0; r < 4; r++) {
                    const float sv = rt ? s1[g2 * 4 + r] : s0[g2 * 4 + r];
                    float p = __expf(sv * SCALE - m4[r]);
                    const unsigned wb = (&w4.x)[r];
                    p = ((wb >> l32) & 1u) ? p : 0.f;
                    ps[r] = p;
                    const int row = rowb + r;
                    const int col = nw * 32 + l32;
                    const int c = col >> 3;
                    const int pc = (c & 56) | ((c & 7) ^ (row & 7));
                    P[row * 512 + pc * 8 + (col & 7)] = (__bf16)p;
                }
                #pragma unroll
                for (int d = 1; d < 32; d <<= 1) {
                    #pragma unroll
                    for (int r = 0; r < 4; r++) ps[r] += __shfl_xor(ps[r], d);
                }
                if (l32 == 0) *(f32x4*)&psum[nw][rowb] = ps;
            }
        }
        __syncthreads();   // B

        // ---- l update (wave 0)
        if (nw == 0) {
            float acc = psum[0][lane];
            #pragma unroll
            for (int w2 = 1; w2 < 16; w2++) acc += psum[w2][lane];
            l_s[lane] = l_s[lane] * alpha_s[lane] + acc;
        }
        // ---- PV: wave d-slice [32nw, +32), rows 0..63
        {
            const __bf16* vb = Vb + (size_t)(nw * 32 + l32) * SEQ + k0 + half * 8;
            #pragma unroll
            for (int ks = 0; ks < 32; ks++) {
                bf16x8 b = *(const bf16x8*)(vb + ks * 16);
                const int c = ks * 2 + half;
                const int r0 = l32, r1 = 32 + l32;
                bf16x8 p0 = *(const bf16x8*)&P[r0 * 512 + (((c & 56) | ((c & 7) ^ (r0 & 7)))) * 8];
                bf16x8 p1 = *(const bf16x8*)&P[r1 * 512 + (((c & 56) | ((c & 7) ^ (r1 & 7)))) * 8];
                o0 = MFMA32(p0, b, o0);
                o1 = MFMA32(p1, b, o1);
            }
        }
    }
    __syncthreads();

    // ---- epilogue: O / l -> AO (aliases Qp rows of this block)
    #pragma unroll
    for (int rt = 0; rt < 2; rt++) {
        #pragma unroll
        for (int g2 = 0; g2 < 4; g2++) {
            const int rowb = rt * 32 + g2 * 8 + half * 4;
            const f32x4 l4 = *(const f32x4*)&l_s[rowb];
            #pragma unroll
            for (int r = 0; r < 4; r++) {
                const float ov = rt ? o1[g2 * 4 + r] : o0[g2 * 4 + r];
                AO[(size_t)(q0 + rowb + r) * DIM + nw * 32 + l32] = (__bf16)(ov / l4[r]);
            }
        }
    }
}

// ---------------------------------------------------------------------------
extern "C" void kernel_launch(void* const* d_in, const int* in_sizes, int n_in,
                              void* d_out, int out_size, void* d_ws, size_t ws_size,
                              hipStream_t stream)
{
    const float* values = (const float*)d_in[0];
    const float* keys   = (const float*)d_in[1];
    const float* query  = (const float*)d_in[2];
    const int*   mask   = (const int*)d_in[3];
    const float* Wv = (const float*)d_in[4];
    const float* Wk = (const float*)d_in[5];
    const float* Wq = (const float*)d_in[6];
    const float* Wo = (const float*)d_in[7];
    const float* bo = (const float*)d_in[8];
    float* out = (float*)d_out;

    char* ws = (char*)d_ws;
    __bf16* Qp  = (__bf16*)(ws);                 // 16 MiB (AO aliases this)
    __bf16* Kp  = (__bf16*)(ws + (16u << 20));   // 16 MiB
    __bf16* Vt  = (__bf16*)(ws + (32u << 20));   // 16 MiB
    __bf16* wbf = (__bf16*)(ws + (48u << 20));   // 2 MiB: Wq,Wk,Wv,Wo bf16

    const int M = 4 * SEQ;  // 16384

    convert_w<<<dim3(128, 4), 256, 0, stream>>>(Wq, Wk, Wv, Wo, wbf);

    gemm_qkv<<<dim3(M / 128, DIM / 128, 3), 256, 0, stream>>>(
        query, keys, values, wbf, Qp, Kp, Vt);

    flash_attn<<<256, 1024, 0, stream>>>(Qp, Kp, Vt, mask);

    gemm_out<<<dim3(M / 128, DIM / 128), 256, 0, stream>>>(
        Qp /*AO*/, wbf + (size_t)3 * DIM * DIM, out, bo);
}